// Round 6
// baseline (1042.401 us; speedup 1.0000x reference)
//
#include <hip/hip_runtime.h>
#include <stdint.h>

#define T_LEN 2048
#define B_TOT 64
#define N_TAG 128

typedef __attribute__((ext_vector_type(4))) float f32x4;
typedef __attribute__((ext_vector_type(8))) short bf16x8;
typedef __attribute__((ext_vector_type(4))) uint32_t u32x4;

template <int S>
struct IC {
  static constexpr int value = S;
};

// pack two fp32 -> dword of two bf16 (round-half-up); elem0 in low half
__device__ __forceinline__ uint32_t pack2_bf16(float a, float b) {
  uint32_t ua = __float_as_uint(a) + 0x8000u;
  uint32_t ub = __float_as_uint(b) + 0x8000u;
  return __builtin_amdgcn_perm(ua, ub, 0x03020706u);
}
__device__ __forceinline__ float bf_lo(uint32_t w) {
  return __uint_as_float(w << 16);
}
__device__ __forceinline__ float bf_hi(uint32_t w) {
  return __uint_as_float(w & 0xffff0000u);
}

// prepass: ws[t][b][i] = bf16(exp(em[b][t][i])), i-pairs packed in u32
__global__ __launch_bounds__(256) void eem_prepass(const float* __restrict__ em,
                                                   uint32_t* __restrict__ ws) {
  const int tid = blockIdx.x * blockDim.x + threadIdx.x;  // 0 .. 2^21-1
  const int b = tid >> 15;
  const int rem = tid & 32767;
  const int t = rem >> 4;
  const int kk = rem & 15;  // 8 floats per thread
  const float4* src =
      (const float4*)(em + ((size_t)b * T_LEN + t) * N_TAG + kk * 8);
  const float4 p0 = src[0];
  const float4 p1 = src[1];
  u32x4 o;
  o[0] = pack2_bf16(__expf(p0.x), __expf(p0.y));
  o[1] = pack2_bf16(__expf(p0.z), __expf(p0.w));
  o[2] = pack2_bf16(__expf(p1.x), __expf(p1.y));
  o[3] = pack2_bf16(__expf(p1.z), __expf(p1.w));
  *(u32x4*)(ws + ((size_t)t * B_TOT + b) * (N_TAG / 2) + kk * 4) = o;
}

// 32 batches/block (2 groups of 16, interleaved), 4 waves/block, 2 blocks.
// Per barrier interval each wave advances BOTH groups one step -- group B's
// compute fills group A's LDS/MFMA latency stalls, and barrier costs amortize
// over 2 steps. A-operand rows permuted so D lands in B-fragment layout
// (register-resident state, 1-write/3-read exchange per group). eem comes
// pre-exponentiated bf16 from the prepass (L3-resident -> short vmcnt drain).
__global__ __launch_bounds__(256, 1) void crf_fwd_kernel(
    const float* __restrict__ em, const int* __restrict__ lens,
    const float* __restrict__ trans, const float* __restrict__ head,
    const float* __restrict__ last, const uint16_t* __restrict__ eem,
    float* __restrict__ out) {
  const int lane = threadIdx.x & 63;
  const int w = threadIdx.x >> 6;  // wave id
  const int c = lane & 15;         // batch-in-tile
  const int q = lane >> 4;
  const int bgg[2] = {(int)blockIdx.x * 32 + c, (int)blockIdx.x * 32 + 16 + c};

  __shared__ u32x4 x_lds[2][2][4][64];  // [group][pingpong][frag u][lane]
  __shared__ int k_lds[2][16];
  __shared__ float cap_lds[2][4][16];

  // E^T fragments (A operand), row-permuted; virtual kt: phys = (w+ktv)&3
  // shared by both groups
  bf16x8 efrag[2][4];
#pragma unroll
  for (int tl = 0; tl < 2; ++tl) {
    const int j = w * 32 + (c >> 2) * 8 + tl * 4 + (c & 3);
#pragma unroll
    for (int ktv = 0; ktv < 4; ++ktv) {
      const int ktp = (w + ktv) & 3;
      u32x4 wd;
#pragma unroll
      for (int p = 0; p < 4; ++p) {
        const int i0 = ktp * 32 + q * 8 + 2 * p;
        wd[p] = pack2_bf16(__expf(trans[(i0 + 0) * N_TAG + j]),
                           __expf(trans[(i0 + 1) * N_TAG + j]));
      }
      efrag[tl][ktv] = __builtin_bit_cast(bf16x8, wd);
    }
  }

  float lastx[8];
#pragma unroll
  for (int jj = 0; jj < 8; ++jj) lastx[jj] = __expf(last[w * 32 + q * 8 + jj]);

  int len[2];
  len[0] = lens[bgg[0]];
  len[1] = lens[bgg[1]];
  float L[2] = {0.f, 0.f}, Lcap[2] = {0.f, 0.f};

  // initial state per group: S0[b][i] = bf16(e^{head_i + em[b][0][i]})
  u32x4 bloc[2];
#pragma unroll
  for (int g = 0; g < 2; ++g) {
    const float* emb = em + (size_t)bgg[g] * T_LEN * N_TAG;
    float v0[8];
#pragma unroll
    for (int jj = 0; jj < 8; ++jj) {
      const int i = w * 32 + q * 8 + jj;
      v0[jj] = __expf(head[i] + emb[i]);
    }
    u32x4 wd;
#pragma unroll
    for (int p = 0; p < 4; ++p) wd[p] = pack2_bf16(v0[2 * p], v0[2 * p + 1]);
    bloc[g] = wd;
    x_lds[g][0][w][lane] = wd;
    if (len[g] == 1) {  // edge (setup guarantees len>=1024; keep correct)
      float s = 0.f;
#pragma unroll
      for (int jj = 0; jj < 8; ++jj) s += v0[jj] * lastx[jj];
      s += __shfl_xor(s, 16);
      s += __shfl_xor(s, 32);
      if (q == 0) cap_lds[g][w][c] = s;
    }
  }
  if (threadIdx.x < 16) {
    k_lds[0][threadIdx.x] = 0;
    k_lds[1][threadIdx.x] = 0;
  }
  __syncthreads();
#pragma unroll
  for (int g = 0; g < 2; ++g)
    if (len[g] == 1 && threadIdx.x < 16)
      out[bgg[g]] = __logf(cap_lds[g][0][c] + cap_lds[g][1][c] +
                           cap_lds[g][2][c] + cap_lds[g][3][c]);

  // eem prefetch slots: slot t&3 holds row t (this wave's 8 j's, bf16)
  u32x4 eslot[2][4];
  auto issue_eem = [&](auto gc, auto sc, int row) {
    constexpr int G = decltype(gc)::value;
    constexpr int S = decltype(sc)::value;
    const uint16_t* p =
        eem + ((size_t)row * B_TOT + bgg[G]) * N_TAG + w * 32 + q * 8;
    eslot[G][S] = *(const u32x4*)p;
  };
  issue_eem(IC<0>{}, IC<1>{}, 1);
  issue_eem(IC<1>{}, IC<1>{}, 1);
  issue_eem(IC<0>{}, IC<2>{}, 2);
  issue_eem(IC<1>{}, IC<2>{}, 2);
  issue_eem(IC<0>{}, IC<3>{}, 3);
  issue_eem(IC<1>{}, IC<3>{}, 3);

  const f32x4 vzero = {0.f, 0.f, 0.f, 0.f};

  // one group's step: unpack eem, 8 MFMAs, capture, probe, pack+write
  auto gstep = [&](auto gc, auto slotc, int t, const u32x4& bf1,
                   const u32x4& bf2, const u32x4& bf3) {
    constexpr int G = decltype(gc)::value;
    constexpr int SLOT = decltype(slotc)::value;
    constexpr int WP = SLOT & 1;
    const u32x4 ev = eslot[G][SLOT];
    float f[8];
    f[0] = bf_lo(ev[0]);
    f[1] = bf_hi(ev[0]);
    f[2] = bf_lo(ev[1]);
    f[3] = bf_hi(ev[1]);
    f[4] = bf_lo(ev[2]);
    f[5] = bf_hi(ev[2]);
    f[6] = bf_lo(ev[3]);
    f[7] = bf_hi(ev[3]);
    if (SLOT == 1) {
      const int e = k_lds[G][c];
      const float sc = __uint_as_float((uint32_t)(127 - e) << 23);
#pragma unroll
      for (int jj = 0; jj < 8; ++jj) f[jj] *= sc;
      L[G] += (float)e * 0.6931471805599453f;
    }
    // MFMA: local frag first (no read dependency), two 2-deep chains
    f32x4 a0 = __builtin_amdgcn_mfma_f32_16x16x32_bf16(
        efrag[0][0], __builtin_bit_cast(bf16x8, bloc[G]), vzero, 0, 0, 0);
    f32x4 a1 = __builtin_amdgcn_mfma_f32_16x16x32_bf16(
        efrag[1][0], __builtin_bit_cast(bf16x8, bloc[G]), vzero, 0, 0, 0);
    f32x4 b0 = __builtin_amdgcn_mfma_f32_16x16x32_bf16(
        efrag[0][1], __builtin_bit_cast(bf16x8, bf1), vzero, 0, 0, 0);
    f32x4 b1 = __builtin_amdgcn_mfma_f32_16x16x32_bf16(
        efrag[1][1], __builtin_bit_cast(bf16x8, bf1), vzero, 0, 0, 0);
    a0 = __builtin_amdgcn_mfma_f32_16x16x32_bf16(
        efrag[0][2], __builtin_bit_cast(bf16x8, bf2), a0, 0, 0, 0);
    a1 = __builtin_amdgcn_mfma_f32_16x16x32_bf16(
        efrag[1][2], __builtin_bit_cast(bf16x8, bf2), a1, 0, 0, 0);
    b0 = __builtin_amdgcn_mfma_f32_16x16x32_bf16(
        efrag[0][3], __builtin_bit_cast(bf16x8, bf3), b0, 0, 0, 0);
    b1 = __builtin_amdgcn_mfma_f32_16x16x32_bf16(
        efrag[1][3], __builtin_bit_cast(bf16x8, bf3), b1, 0, 0, 0);
    const f32x4 acc0 = a0 + b0;
    const f32x4 acc1 = a1 + b1;
    if (t == len[G] - 1) {
      float s = acc0[0] * f[0] * lastx[0] + acc0[1] * f[1] * lastx[1] +
                acc0[2] * f[2] * lastx[2] + acc0[3] * f[3] * lastx[3] +
                acc1[0] * f[4] * lastx[4] + acc1[1] * f[5] * lastx[5] +
                acc1[2] * f[6] * lastx[6] + acc1[3] * f[7] * lastx[7];
      s += __shfl_xor(s, 16);
      s += __shfl_xor(s, 32);
      if (q == 0) cap_lds[G][w][c] = s;
      Lcap[G] = L[G];
    }
    if (SLOT == 0) {
      // exponent probe of j=0 (wave 0, q==0 lanes): acc0[0] = alpha[0][c]
      if (threadIdx.x < 16)
        k_lds[G][c] = (int)(__float_as_uint(acc0[0]) >> 23) - 126;
    }
    u32x4 wd;
    wd[0] = pack2_bf16(acc0[0] * f[0], acc0[1] * f[1]);
    wd[1] = pack2_bf16(acc0[2] * f[2], acc0[3] * f[3]);
    wd[2] = pack2_bf16(acc1[0] * f[4], acc1[1] * f[5]);
    wd[3] = pack2_bf16(acc1[2] * f[6], acc1[3] * f[7]);
    bloc[G] = wd;
    x_lds[G][WP][w][lane] = wd;
  };

  auto step = [&](auto slotc, int t) {
    constexpr int SLOT = decltype(slotc)::value;
    constexpr int RP = (SLOT + 1) & 1;  // read buffer (state of t-1)
    int row = t + 3;
    if (row > T_LEN - 1) row = T_LEN - 1;
    issue_eem(IC<0>{}, IC<(SLOT + 3) & 3>{}, row);
    issue_eem(IC<1>{}, IC<(SLOT + 3) & 3>{}, row);
    // all remote fragment reads up front (both groups)
    const u32x4 a1 = x_lds[0][RP][(w + 1) & 3][lane];
    const u32x4 a2 = x_lds[0][RP][(w + 2) & 3][lane];
    const u32x4 a3 = x_lds[0][RP][(w + 3) & 3][lane];
    const u32x4 b1 = x_lds[1][RP][(w + 1) & 3][lane];
    const u32x4 b2 = x_lds[1][RP][(w + 2) & 3][lane];
    const u32x4 b3 = x_lds[1][RP][(w + 3) & 3][lane];
    gstep(IC<0>{}, slotc, t, a1, a2, a3);
    gstep(IC<1>{}, slotc, t, b1, b2, b3);
    __syncthreads();
    if (t == len[0] - 1 && threadIdx.x < 16)
      out[bgg[0]] = __logf(cap_lds[0][0][c] + cap_lds[0][1][c] +
                           cap_lds[0][2][c] + cap_lds[0][3][c]) +
                    Lcap[0];
    if (t == len[1] - 1 && threadIdx.x < 16)
      out[bgg[1]] = __logf(cap_lds[1][0][c] + cap_lds[1][1][c] +
                           cap_lds[1][2][c] + cap_lds[1][3][c]) +
                    Lcap[1];
  };

  int t = 1;
#pragma unroll 1
  for (int it = 0; it < 511; ++it) {  // t = 1 .. 2044
    step(IC<1>{}, t);
    step(IC<2>{}, t + 1);
    step(IC<3>{}, t + 2);
    step(IC<0>{}, t + 3);
    t += 4;
  }
  step(IC<1>{}, t);      // 2045
  step(IC<2>{}, t + 1);  // 2046
  step(IC<3>{}, t + 2);  // 2047
}

extern "C" void kernel_launch(void* const* d_in, const int* in_sizes, int n_in,
                              void* d_out, int out_size, void* d_ws,
                              size_t ws_size, hipStream_t stream) {
  const float* em = (const float*)d_in[0];
  const int* lens = (const int*)d_in[1];
  const float* trans = (const float*)d_in[2];
  const float* head = (const float*)d_in[3];
  const float* last = (const float*)d_in[4];
  float* out = (float*)d_out;
  uint32_t* ws = (uint32_t*)d_ws;  // 2048*64*128 bf16 = 32 MiB

  eem_prepass<<<8192, 256, 0, stream>>>(em, ws);
  crf_fwd_kernel<<<2, 256, 0, stream>>>(em, lens, trans, head, last,
                                        (const uint16_t*)ws, out);
}

// Round 7
// 746.905 us; speedup vs baseline: 1.3956x; 1.3956x over previous
//
#include <hip/hip_runtime.h>
#include <stdint.h>

#define T_LEN 2048
#define B_TOT 64
#define N_TAG 128

typedef __attribute__((ext_vector_type(4))) float f32x4;
typedef __attribute__((ext_vector_type(8))) short bf16x8;
typedef __attribute__((ext_vector_type(4))) uint32_t u32x4;

template <int S>
struct IC {
  static constexpr int value = S;
};

// pack two fp32 -> dword of two bf16 (round-half-up); elem0 in low half
__device__ __forceinline__ uint32_t pack2_bf16(float a, float b) {
  uint32_t ua = __float_as_uint(a) + 0x8000u;
  uint32_t ub = __float_as_uint(b) + 0x8000u;
  return __builtin_amdgcn_perm(ua, ub, 0x03020706u);
}
__device__ __forceinline__ float bf_lo(uint32_t w) {
  return __uint_as_float(w << 16);
}
__device__ __forceinline__ float bf_hi(uint32_t w) {
  return __uint_as_float(w & 0xffff0000u);
}

// prepass: ws[t][b][i] = bf16(exp(em[b][t][i])), i-pairs packed in u32
__global__ __launch_bounds__(256) void eem_prepass(const float* __restrict__ em,
                                                   uint32_t* __restrict__ ws) {
  const int tid = blockIdx.x * blockDim.x + threadIdx.x;  // 0 .. 2^21-1
  const int b = tid >> 15;
  const int rem = tid & 32767;
  const int t = rem >> 4;
  const int kk = rem & 15;  // 8 floats per thread
  const float4* src =
      (const float4*)(em + ((size_t)b * T_LEN + t) * N_TAG + kk * 8);
  const float4 p0 = src[0];
  const float4 p1 = src[1];
  u32x4 o;
  o[0] = pack2_bf16(__expf(p0.x), __expf(p0.y));
  o[1] = pack2_bf16(__expf(p0.z), __expf(p0.w));
  o[2] = pack2_bf16(__expf(p1.x), __expf(p1.y));
  o[3] = pack2_bf16(__expf(p1.z), __expf(p1.w));
  *(u32x4*)(ws + ((size_t)t * B_TOT + b) * (N_TAG / 2) + kk * 4) = o;
}

// 2 blocks x 512 threads (8 waves). Waves 0-3 = batch-group A (16 batches),
// waves 4-7 = group B -- each SIMD hosts one wave of EACH group, giving two
// independent HW instruction streams per SIMD (hardware latency hiding,
// unlike R6's single-stream software interleave). Within a group: R4's
// 4-wave j-split with permuted A rows (D lands in next step's B-fragment
// layout; state register-resident; 1-write/3-read LDS exchange). eem is
// pre-exponentiated bf16 (L3-resident). Rescale: j=0 exponent probe.
__global__ __launch_bounds__(512, 2) void crf_fwd_kernel(
    const float* __restrict__ em, const int* __restrict__ lens,
    const float* __restrict__ trans, const float* __restrict__ head,
    const float* __restrict__ last, const uint32_t* __restrict__ eem,
    float* __restrict__ out) {
  const int lane = threadIdx.x & 63;
  const int wv = threadIdx.x >> 6;  // 0..7
  const int g = wv >> 2;            // batch group
  const int wg = wv & 3;            // wave-in-group (j-chunk)
  const int c = lane & 15;          // batch-in-tile
  const int q = lane >> 4;
  const int bg = (int)blockIdx.x * 32 + g * 16 + c;

  __shared__ u32x4 x_lds[2][2][4][64];  // [group][pingpong][frag u][lane]
  __shared__ int k_lds[2][16];
  __shared__ float cap_lds[2][4][16];

  // E^T fragments (A operand), row-permuted; virtual kt: phys = (wg+ktv)&3
  bf16x8 efrag[2][4];
#pragma unroll
  for (int tl = 0; tl < 2; ++tl) {
    const int j = wg * 32 + (c >> 2) * 8 + tl * 4 + (c & 3);
#pragma unroll
    for (int ktv = 0; ktv < 4; ++ktv) {
      const int ktp = (wg + ktv) & 3;
      u32x4 wd;
#pragma unroll
      for (int p = 0; p < 4; ++p) {
        const int i0 = ktp * 32 + q * 8 + 2 * p;
        wd[p] = pack2_bf16(__expf(trans[(i0 + 0) * N_TAG + j]),
                           __expf(trans[(i0 + 1) * N_TAG + j]));
      }
      efrag[tl][ktv] = __builtin_bit_cast(bf16x8, wd);
    }
  }

  float lastx[8];
#pragma unroll
  for (int jj = 0; jj < 8; ++jj) lastx[jj] = __expf(last[wg * 32 + q * 8 + jj]);

  const int len = lens[bg];
  float L = 0.f, Lcap = 0.f;

  // initial state: S0[b][i] = bf16(e^{head_i + em[b][0][i]}), i=32wg+8q+jj
  const float* emb = em + (size_t)bg * T_LEN * N_TAG;
  float v0[8];
#pragma unroll
  for (int jj = 0; jj < 8; ++jj) {
    const int i = wg * 32 + q * 8 + jj;
    v0[jj] = __expf(head[i] + emb[i]);
  }
  u32x4 bloc;
#pragma unroll
  for (int p = 0; p < 4; ++p) bloc[p] = pack2_bf16(v0[2 * p], v0[2 * p + 1]);
  x_lds[g][0][wg][lane] = bloc;
  if (threadIdx.x < 16) {
    k_lds[0][threadIdx.x] = 0;
    k_lds[1][threadIdx.x] = 0;
  }
  if (len == 1) {  // edge (setup guarantees len>=1024; keep correct)
    float s = 0.f;
#pragma unroll
    for (int jj = 0; jj < 8; ++jj) s += v0[jj] * lastx[jj];
    s += __shfl_xor(s, 16);
    s += __shfl_xor(s, 32);
    if (q == 0) cap_lds[g][wg][c] = s;
  }
  __syncthreads();
  if (len == 1 && wg == 0 && lane < 16)
    out[bg] = __logf(cap_lds[g][0][c] + cap_lds[g][1][c] + cap_lds[g][2][c] +
                     cap_lds[g][3][c]);

  // eem prefetch: slot t&3 holds row t (this wave's 8 j's = u32x4, D-order)
  const size_t lane_off = (size_t)bg * 64 + wg * 16 + q * 4;
  u32x4 eslot[4];
  auto issue_eem = [&](auto sc, int row) {
    constexpr int S = decltype(sc)::value;
    eslot[S] = *(const u32x4*)(eem + (size_t)row * 4096 + lane_off);
  };
  issue_eem(IC<1>{}, 1);
  issue_eem(IC<2>{}, 2);
  issue_eem(IC<3>{}, 3);

  const f32x4 vzero = {0.f, 0.f, 0.f, 0.f};

  auto step = [&](auto slotc, int t) {
    constexpr int SLOT = decltype(slotc)::value;
    constexpr int RP = (SLOT + 1) & 1;  // read buffer (state of t-1)
    constexpr int WP = SLOT & 1;        // write buffer
    // prefetch first (vmem issue before LDS dependencies)
    {
      int row = t + 3;
      if (row > T_LEN - 1) row = T_LEN - 1;
      issue_eem(IC<(SLOT + 3) & 3>{}, row);
    }
    int e = 0;
    if (SLOT == 1) e = k_lds[g][c];
    // remote fragment reads
    const u32x4 bf1 = x_lds[g][RP][(wg + 1) & 3][lane];
    const u32x4 bf2 = x_lds[g][RP][(wg + 2) & 3][lane];
    const u32x4 bf3 = x_lds[g][RP][(wg + 3) & 3][lane];
    // unpack eem (no LDS dependency)
    const u32x4 ev = eslot[SLOT];
    float f[8];
    f[0] = bf_lo(ev[0]);
    f[1] = bf_hi(ev[0]);
    f[2] = bf_lo(ev[1]);
    f[3] = bf_hi(ev[1]);
    f[4] = bf_lo(ev[2]);
    f[5] = bf_hi(ev[2]);
    f[6] = bf_lo(ev[3]);
    f[7] = bf_hi(ev[3]);
    if (SLOT == 1) {
      const float sc = __uint_as_float((uint32_t)(127 - e) << 23);
#pragma unroll
      for (int jj = 0; jj < 8; ++jj) f[jj] *= sc;
      L += (float)e * 0.6931471805599453f;
    }
    // two independent 4-deep MFMA chains (partner wave hides dep latency)
    f32x4 a0 = __builtin_amdgcn_mfma_f32_16x16x32_bf16(
        efrag[0][0], __builtin_bit_cast(bf16x8, bloc), vzero, 0, 0, 0);
    f32x4 a1 = __builtin_amdgcn_mfma_f32_16x16x32_bf16(
        efrag[1][0], __builtin_bit_cast(bf16x8, bloc), vzero, 0, 0, 0);
    a0 = __builtin_amdgcn_mfma_f32_16x16x32_bf16(
        efrag[0][1], __builtin_bit_cast(bf16x8, bf1), a0, 0, 0, 0);
    a1 = __builtin_amdgcn_mfma_f32_16x16x32_bf16(
        efrag[1][1], __builtin_bit_cast(bf16x8, bf1), a1, 0, 0, 0);
    a0 = __builtin_amdgcn_mfma_f32_16x16x32_bf16(
        efrag[0][2], __builtin_bit_cast(bf16x8, bf2), a0, 0, 0, 0);
    a1 = __builtin_amdgcn_mfma_f32_16x16x32_bf16(
        efrag[1][2], __builtin_bit_cast(bf16x8, bf2), a1, 0, 0, 0);
    a0 = __builtin_amdgcn_mfma_f32_16x16x32_bf16(
        efrag[0][3], __builtin_bit_cast(bf16x8, bf3), a0, 0, 0, 0);
    a1 = __builtin_amdgcn_mfma_f32_16x16x32_bf16(
        efrag[1][3], __builtin_bit_cast(bf16x8, bf3), a1, 0, 0, 0);
    // capture: out_b = log(sum_j acc*eem*e^{last}) + L  (this wave's 8 j's)
    if (t == len - 1) {
      float s = a0[0] * f[0] * lastx[0] + a0[1] * f[1] * lastx[1] +
                a0[2] * f[2] * lastx[2] + a0[3] * f[3] * lastx[3] +
                a1[0] * f[4] * lastx[4] + a1[1] * f[5] * lastx[5] +
                a1[2] * f[6] * lastx[6] + a1[3] * f[7] * lastx[7];
      s += __shfl_xor(s, 16);
      s += __shfl_xor(s, 32);
      if (q == 0) cap_lds[g][wg][c] = s;
      Lcap = L;
    }
    if (SLOT == 0) {
      // exponent probe of j=0: wave wg==0, q==0 lanes hold alpha[j=0][c]
      if (wg == 0 && lane < 16)
        k_lds[g][c] = (int)(__float_as_uint(a0[0]) >> 23) - 126;
    }
    // pack next state frag (already in B-fragment layout -- lane-local)
    u32x4 wd;
    wd[0] = pack2_bf16(a0[0] * f[0], a0[1] * f[1]);
    wd[1] = pack2_bf16(a0[2] * f[2], a0[3] * f[3]);
    wd[2] = pack2_bf16(a1[0] * f[4], a1[1] * f[5]);
    wd[3] = pack2_bf16(a1[2] * f[6], a1[3] * f[7]);
    bloc = wd;
    x_lds[g][WP][wg][lane] = wd;
    __syncthreads();
    if (t == len - 1 && wg == 0 && lane < 16)
      out[bg] = __logf(cap_lds[g][0][c] + cap_lds[g][1][c] + cap_lds[g][2][c] +
                       cap_lds[g][3][c]) +
                Lcap;
  };

  int t = 1;
#pragma unroll 1
  for (int it = 0; it < 511; ++it) {  // t = 1 .. 2044
    step(IC<1>{}, t);
    step(IC<2>{}, t + 1);
    step(IC<3>{}, t + 2);
    step(IC<0>{}, t + 3);
    t += 4;
  }
  step(IC<1>{}, t);      // 2045
  step(IC<2>{}, t + 1);  // 2046
  step(IC<3>{}, t + 2);  // 2047
}

extern "C" void kernel_launch(void* const* d_in, const int* in_sizes, int n_in,
                              void* d_out, int out_size, void* d_ws,
                              size_t ws_size, hipStream_t stream) {
  const float* em = (const float*)d_in[0];
  const int* lens = (const int*)d_in[1];
  const float* trans = (const float*)d_in[2];
  const float* head = (const float*)d_in[3];
  const float* last = (const float*)d_in[4];
  float* out = (float*)d_out;
  uint32_t* ws = (uint32_t*)d_ws;  // 2048*64*128 bf16 = 32 MiB

  eem_prepass<<<8192, 256, 0, stream>>>(em, ws);
  crf_fwd_kernel<<<2, 512, 0, stream>>>(em, lens, trans, head, last, ws, out);
}

// Round 8
// 597.261 us; speedup vs baseline: 1.7453x; 1.2506x over previous
//
#include <hip/hip_runtime.h>
#include <stdint.h>

#define T_LEN 2048
#define B_TOT 64
#define N_TAG 128

typedef __attribute__((ext_vector_type(4))) float f32x4;
typedef __attribute__((ext_vector_type(8))) short bf16x8;
typedef __attribute__((ext_vector_type(4))) uint32_t u32x4;
typedef __attribute__((ext_vector_type(2))) uint32_t u32x2;

template <int S>
struct IC {
  static constexpr int value = S;
};

// pack two fp32 -> dword of two bf16 (round-half-up); elem0 in low half
__device__ __forceinline__ uint32_t pack2_bf16(float a, float b) {
  uint32_t ua = __float_as_uint(a) + 0x8000u;
  uint32_t ub = __float_as_uint(b) + 0x8000u;
  return __builtin_amdgcn_perm(ua, ub, 0x03020706u);
}
__device__ __forceinline__ float bf_lo(uint32_t w) {
  return __uint_as_float(w << 16);
}
__device__ __forceinline__ float bf_hi(uint32_t w) {
  return __uint_as_float(w & 0xffff0000u);
}

// prepass: ws[t][b][i] = bf16(exp(em[b][t][i])), i-pairs packed in u32
__global__ __launch_bounds__(256) void eem_prepass(const float* __restrict__ em,
                                                   uint32_t* __restrict__ ws) {
  const int tid = blockIdx.x * blockDim.x + threadIdx.x;  // 0 .. 2^21-1
  const int b = tid >> 15;
  const int rem = tid & 32767;
  const int t = rem >> 4;
  const int kk = rem & 15;  // 8 floats per thread
  const float4* src =
      (const float4*)(em + ((size_t)b * T_LEN + t) * N_TAG + kk * 8);
  const float4 p0 = src[0];
  const float4 p1 = src[1];
  u32x4 o;
  o[0] = pack2_bf16(__expf(p0.x), __expf(p0.y));
  o[1] = pack2_bf16(__expf(p0.z), __expf(p0.w));
  o[2] = pack2_bf16(__expf(p1.x), __expf(p1.y));
  o[3] = pack2_bf16(__expf(p1.z), __expf(p1.w));
  *(u32x4*)(ws + ((size_t)t * B_TOT + b) * (N_TAG / 2) + kk * 4) = o;
}

// 4 blocks x 512 threads (8 waves) = 16 batches/block on 4 CUs, 2 waves/SIMD.
// 8-way j-split: wave w owns 16 j's (one MFMA tile), 4 MFMAs/step. A rows
// permuted per wave: j = (w>>1)*32 + (m>>2)*8 + (w&1)*4 + (m&3), so the f32x4
// D output IS the half-fragment (frag w>>1, half w&1) of next step's B
// operand: 1 ds_write_b64 + 4 ds_read_b128 per wave per step. Two waves per
// SIMD give two independent HW instruction streams (R7 showed 1.86x per-CU
// efficiency from this; R7's mistake was running on 2 CUs). eem is
// pre-exponentiated bf16 (L3-resident). Rescale: j=0 exponent probe.
__global__ __launch_bounds__(512, 2) void crf_fwd_kernel(
    const float* __restrict__ em, const int* __restrict__ lens,
    const float* __restrict__ trans, const float* __restrict__ head,
    const float* __restrict__ last, const uint32_t* __restrict__ eem,
    float* __restrict__ out) {
  const int lane = threadIdx.x & 63;
  const int w = threadIdx.x >> 6;  // 0..7
  const int f = w >> 1;            // owned fragment
  const int h = w & 1;             // half within fragment
  const int c = lane & 15;         // batch-in-tile
  const int q = lane >> 4;
  const int bg = (int)blockIdx.x * 16 + c;
  const int jbase = f * 32 + q * 8 + h * 4;  // lane's 4 j's: jbase + r

  __shared__ uint32_t x_lds[2][4][64][4];  // [pingpong][frag][lane][dword]
  __shared__ int k_lds[16];
  __shared__ float cap_lds[8][16];

  // A fragments, row-permuted; virtual kt rotation staggers LDS access
  bf16x8 efrag[4];
  {
    const int j = f * 32 + (c >> 2) * 8 + h * 4 + (c & 3);
#pragma unroll
    for (int ktv = 0; ktv < 4; ++ktv) {
      const int ktp = (w + ktv) & 3;
      u32x4 wd;
#pragma unroll
      for (int p = 0; p < 4; ++p) {
        const int i0 = ktp * 32 + q * 8 + 2 * p;
        wd[p] = pack2_bf16(__expf(trans[(i0 + 0) * N_TAG + j]),
                           __expf(trans[(i0 + 1) * N_TAG + j]));
      }
      efrag[ktv] = __builtin_bit_cast(bf16x8, wd);
    }
  }

  float lastx[4];
#pragma unroll
  for (int r = 0; r < 4; ++r) lastx[r] = __expf(last[jbase + r]);

  const int len = lens[bg];
  float L = 0.f, Lcap = 0.f;

  // initial state: S0[b][i] = bf16(e^{head_i + em[b][0][i]}); this wave's
  // half-fragment indices i = jbase + r (coincides with its j range)
  const float* emb = em + (size_t)bg * T_LEN * N_TAG;
  float v0[4];
#pragma unroll
  for (int r = 0; r < 4; ++r) v0[r] = __expf(head[jbase + r] + emb[jbase + r]);
  {
    u32x2 wd;
    wd[0] = pack2_bf16(v0[0], v0[1]);
    wd[1] = pack2_bf16(v0[2], v0[3]);
    *(u32x2*)&x_lds[0][f][lane][h * 2] = wd;
  }
  if (w == 0 && lane < 16) k_lds[lane] = 0;
  if (len == 1) {  // edge (setup guarantees len>=1024; keep correct)
    float s = v0[0] * lastx[0] + v0[1] * lastx[1] + v0[2] * lastx[2] +
              v0[3] * lastx[3];
    s += __shfl_xor(s, 16);
    s += __shfl_xor(s, 32);
    if (q == 0) cap_lds[w][c] = s;
  }
  __syncthreads();
  if (len == 1 && w == 0 && lane < 16) {
    float s = 0.f;
#pragma unroll
    for (int u = 0; u < 8; ++u) s += cap_lds[u][c];
    out[bg] = __logf(s);
  }

  // eem prefetch: slot t&3 holds row t (this lane's 4 j's = u32x2)
  const size_t eoff = (size_t)bg * 64 + f * 16 + q * 4 + h * 2;
  u32x2 eslot[4];
  auto issue_eem = [&](auto sc, int row) {
    constexpr int S = decltype(sc)::value;
    eslot[S] = *(const u32x2*)(eem + (size_t)row * 4096 + eoff);
  };
  issue_eem(IC<1>{}, 1);
  issue_eem(IC<2>{}, 2);
  issue_eem(IC<3>{}, 3);

  const f32x4 vzero = {0.f, 0.f, 0.f, 0.f};

  auto step = [&](auto slotc, int t) {
    constexpr int SLOT = decltype(slotc)::value;
    constexpr int RP = (SLOT + 1) & 1;  // read buffer (state of t-1)
    constexpr int WP = SLOT & 1;        // write buffer
    // prefetch first (vmem issue before LDS dependencies)
    {
      int row = t + 3;
      if (row > T_LEN - 1) row = T_LEN - 1;
      issue_eem(IC<(SLOT + 3) & 3>{}, row);
    }
    int e = 0;
    if (SLOT == 1) e = k_lds[c];
    // B fragments from LDS (full state; own half included)
    u32x4 bfr[4];
#pragma unroll
    for (int ktv = 0; ktv < 4; ++ktv)
      bfr[ktv] = *(const u32x4*)&x_lds[RP][(w + ktv) & 3][lane][0];
    // unpack eem (no LDS dependency)
    const u32x2 ev = eslot[SLOT];
    float ff[4];
    ff[0] = bf_lo(ev[0]);
    ff[1] = bf_hi(ev[0]);
    ff[2] = bf_lo(ev[1]);
    ff[3] = bf_hi(ev[1]);
    if (SLOT == 1) {
      const float sc = __uint_as_float((uint32_t)(127 - e) << 23);
#pragma unroll
      for (int r = 0; r < 4; ++r) ff[r] *= sc;
      L += (float)e * 0.6931471805599453f;
    }
    // 4-deep MFMA chain (partner wave on this SIMD hides dep latency)
    f32x4 acc = __builtin_amdgcn_mfma_f32_16x16x32_bf16(
        efrag[0], __builtin_bit_cast(bf16x8, bfr[0]), vzero, 0, 0, 0);
    acc = __builtin_amdgcn_mfma_f32_16x16x32_bf16(
        efrag[1], __builtin_bit_cast(bf16x8, bfr[1]), acc, 0, 0, 0);
    acc = __builtin_amdgcn_mfma_f32_16x16x32_bf16(
        efrag[2], __builtin_bit_cast(bf16x8, bfr[2]), acc, 0, 0, 0);
    acc = __builtin_amdgcn_mfma_f32_16x16x32_bf16(
        efrag[3], __builtin_bit_cast(bf16x8, bfr[3]), acc, 0, 0, 0);
    // capture: out_b = log(sum_j acc*eem*e^{last}) + L  (this lane's 4 j's)
    if (t == len - 1) {
      float s = acc[0] * ff[0] * lastx[0] + acc[1] * ff[1] * lastx[1] +
                acc[2] * ff[2] * lastx[2] + acc[3] * ff[3] * lastx[3];
      s += __shfl_xor(s, 16);
      s += __shfl_xor(s, 32);
      if (q == 0) cap_lds[w][c] = s;
      Lcap = L;
    }
    if (SLOT == 0) {
      // exponent probe of j=0: wave 0, lanes 0-15 (q=0,r=0) hold alpha[0][c]
      if (w == 0 && lane < 16)
        k_lds[c] = (int)(__float_as_uint(acc[0]) >> 23) - 126;
    }
    // pack next state half-frag (already in B-fragment layout -- lane-local)
    u32x2 wd;
    wd[0] = pack2_bf16(acc[0] * ff[0], acc[1] * ff[1]);
    wd[1] = pack2_bf16(acc[2] * ff[2], acc[3] * ff[3]);
    *(u32x2*)&x_lds[WP][f][lane][h * 2] = wd;
    __syncthreads();
    if (t == len - 1 && w == 0 && lane < 16) {
      float s = 0.f;
#pragma unroll
      for (int u = 0; u < 8; ++u) s += cap_lds[u][c];
      out[bg] = __logf(s) + Lcap;
    }
  };

  int t = 1;
#pragma unroll 1
  for (int it = 0; it < 511; ++it) {  // t = 1 .. 2044
    step(IC<1>{}, t);
    step(IC<2>{}, t + 1);
    step(IC<3>{}, t + 2);
    step(IC<0>{}, t + 3);
    t += 4;
  }
  step(IC<1>{}, t);      // 2045
  step(IC<2>{}, t + 1);  // 2046
  step(IC<3>{}, t + 2);  // 2047
}

extern "C" void kernel_launch(void* const* d_in, const int* in_sizes, int n_in,
                              void* d_out, int out_size, void* d_ws,
                              size_t ws_size, hipStream_t stream) {
  const float* em = (const float*)d_in[0];
  const int* lens = (const int*)d_in[1];
  const float* trans = (const float*)d_in[2];
  const float* head = (const float*)d_in[3];
  const float* last = (const float*)d_in[4];
  float* out = (float*)d_out;
  uint32_t* ws = (uint32_t*)d_ws;  // 2048*64*128 bf16 = 32 MiB

  eem_prepass<<<8192, 256, 0, stream>>>(em, ws);
  crf_fwd_kernel<<<4, 512, 0, stream>>>(em, lens, trans, head, last, ws, out);
}